// Round 1
// baseline (379.136 us; speedup 1.0000x reference)
//
#include <hip/hip_runtime.h>
#include <hip/hip_bf16.h>

#define DIMC 192
#define HEADS 6
#define CH 32
#define NSEQ 8192
#define NB 2
#define NMEM 48
#define PE_N 2601
#define NTOT (NB * NSEQ)   // 16384 query rows total

// ---------------- PE table: (2601,5) @ Wpe^T (5->6) + bpe ----------------
__global__ void pe_kernel(const float* __restrict__ pre_table,
                          const float* __restrict__ Wpe,
                          const float* __restrict__ bpe,
                          float* __restrict__ pe_out) {
    int i = blockIdx.x * blockDim.x + threadIdx.x;
    if (i >= PE_N) return;
    float p0 = pre_table[i * 5 + 0], p1 = pre_table[i * 5 + 1], p2 = pre_table[i * 5 + 2];
    float p3 = pre_table[i * 5 + 3], p4 = pre_table[i * 5 + 4];
#pragma unroll
    for (int h = 0; h < HEADS; ++h) {
        float s = bpe[h] + p0 * Wpe[h * 5 + 0] + p1 * Wpe[h * 5 + 1] + p2 * Wpe[h * 5 + 2]
                + p3 * Wpe[h * 5 + 3] + p4 * Wpe[h * 5 + 4];
        pe_out[i * HEADS + h] = s;
    }
}

// ---------------- fp32 tiled GEMM: C[i][o] = dot(A[i,:], W[o,:]) ----------------
// mode 0: qkv  (N=576; o<192 -> q scaled; o>=192 -> de-interleave k/v)
// mode 1: proj (N=192; writes oq = out + bias)
#define BM 64
#define BN 64
#define BK 32
__global__ __launch_bounds__(256) void gemm_kernel(
    const float* __restrict__ A,
    const float* __restrict__ W0,
    const float* __restrict__ Wkv,
    const float* __restrict__ b0,
    const float* __restrict__ bkv,
    float* __restrict__ oq,
    float* __restrict__ ok,
    float* __restrict__ ov,
    const int mode) {
    __shared__ float As[BK][BM];
    __shared__ float Ws[BK][BN];
    const int tid = threadIdx.x;
    const int tx = tid & 15, ty = tid >> 4;
    const size_t rowbase = (size_t)blockIdx.x * BM;
    const int colbase = blockIdx.y * BN;

    const float* Wsel;
    if (mode == 0 && colbase >= DIMC)
        Wsel = Wkv + (size_t)(colbase - DIMC) * DIMC;
    else
        Wsel = W0 + (size_t)colbase * DIMC;

    float acc[4][4] = {};

    const int lrow = tid >> 3;         // 0..31
    const int lcol = (tid & 7) << 2;   // 0,4,...,28

    for (int k0 = 0; k0 < DIMC; k0 += BK) {
        // global -> regs (issued before barrier so they overlap the wait)
        float4 a0 = *reinterpret_cast<const float4*>(A + (rowbase + lrow) * DIMC + k0 + lcol);
        float4 a1 = *reinterpret_cast<const float4*>(A + (rowbase + lrow + 32) * DIMC + k0 + lcol);
        float4 w0 = *reinterpret_cast<const float4*>(Wsel + (size_t)lrow * DIMC + k0 + lcol);
        float4 w1 = *reinterpret_cast<const float4*>(Wsel + (size_t)(lrow + 32) * DIMC + k0 + lcol);
        __syncthreads();   // previous iteration's compute must finish reading LDS
        As[lcol + 0][lrow] = a0.x; As[lcol + 1][lrow] = a0.y; As[lcol + 2][lrow] = a0.z; As[lcol + 3][lrow] = a0.w;
        As[lcol + 0][lrow + 32] = a1.x; As[lcol + 1][lrow + 32] = a1.y; As[lcol + 2][lrow + 32] = a1.z; As[lcol + 3][lrow + 32] = a1.w;
        Ws[lcol + 0][lrow] = w0.x; Ws[lcol + 1][lrow] = w0.y; Ws[lcol + 2][lrow] = w0.z; Ws[lcol + 3][lrow] = w0.w;
        Ws[lcol + 0][lrow + 32] = w1.x; Ws[lcol + 1][lrow + 32] = w1.y; Ws[lcol + 2][lrow + 32] = w1.z; Ws[lcol + 3][lrow + 32] = w1.w;
        __syncthreads();
#pragma unroll
        for (int kk = 0; kk < BK; ++kk) {
            float4 av = *reinterpret_cast<const float4*>(&As[kk][ty << 2]);
            float4 wv = *reinterpret_cast<const float4*>(&Ws[kk][tx << 2]);
            float aa[4] = {av.x, av.y, av.z, av.w};
            float ww[4] = {wv.x, wv.y, wv.z, wv.w};
#pragma unroll
            for (int u = 0; u < 4; ++u)
#pragma unroll
                for (int w = 0; w < 4; ++w) acc[u][w] += aa[u] * ww[w];
        }
    }

    const int o0 = colbase + (tx << 2);
#pragma unroll
    for (int u = 0; u < 4; ++u) {
        const size_t i = rowbase + (ty << 2) + u;
        if (mode == 1) {
            float4 r;
            r.x = acc[u][0] + b0[o0 + 0];
            r.y = acc[u][1] + b0[o0 + 1];
            r.z = acc[u][2] + b0[o0 + 2];
            r.w = acc[u][3] + b0[o0 + 3];
            *reinterpret_cast<float4*>(oq + i * DIMC + o0) = r;
        } else if (o0 < DIMC) {
            const float s = 0.17677669529663687f;  // 1/sqrt(32)
            float4 r;
            r.x = (acc[u][0] + b0[o0 + 0]) * s;
            r.y = (acc[u][1] + b0[o0 + 1]) * s;
            r.z = (acc[u][2] + b0[o0 + 2]) * s;
            r.w = (acc[u][3] + b0[o0 + 3]) * s;
            *reinterpret_cast<float4*>(oq + i * DIMC + o0) = r;
        } else {
            const int t0 = o0 - DIMC;
            float4 r;
            r.x = acc[u][0] + bkv[t0 + 0];
            r.y = acc[u][1] + bkv[t0 + 1];
            r.z = acc[u][2] + bkv[t0 + 2];
            r.w = acc[u][3] + bkv[t0 + 3];
            const int hh = t0 >> 6, rr = t0 & 63;
            float* dst = (rr < CH) ? (ok + i * DIMC + hh * CH + rr)
                                   : (ov + i * DIMC + hh * CH + (rr - CH));
            *reinterpret_cast<float4*>(dst) = r;
        }
    }
}

// ---------------- attention: one wave per query ----------------
// lane l owns channels {l, l+64, l+128}; head of channel cc is cc>>5.
__global__ __launch_bounds__(256) void attn_kernel(
    const float* __restrict__ q, const float* __restrict__ k, const float* __restrict__ v,
    const int* __restrict__ member_idx, const float* __restrict__ cmask,
    const int* __restrict__ pe_idx, const float* __restrict__ peT,
    const float* __restrict__ blank_k, const float* __restrict__ blank_v,
    float* __restrict__ outA) {
    __shared__ float p_lds[4][HEADS][64];
    const int wave = threadIdx.x >> 6;
    const int lane = threadIdx.x & 63;
    const int qi = blockIdx.x * 4 + wave;
    const int bbase = qi & ~(NSEQ - 1);  // b*8192
    const float* qrow = q + (size_t)qi * DIMC;
    const float q0 = qrow[lane], q1 = qrow[lane + 64], q2 = qrow[lane + 128];
    const int h0 = lane >> 5, h1 = 2 + (lane >> 5), h2 = 4 + (lane >> 5);
    const int* mrow = member_idx + (size_t)qi * NMEM;
    const float* maskrow = cmask + (size_t)qi * NMEM;
    const int* perow = pe_idx + (size_t)qi * NMEM;

    for (int mm = 0; mm < NMEM + 1; ++mm) {
        float a0, a1, a2;
        if (mm < NMEM) {
            const int mem = mrow[mm];
            const float* krow = k + (size_t)(bbase + mem) * DIMC;
            a0 = q0 * krow[lane]; a1 = q1 * krow[lane + 64]; a2 = q2 * krow[lane + 128];
        } else {
            a0 = q0 * blank_k[lane]; a1 = q1 * blank_k[lane + 64]; a2 = q2 * blank_k[lane + 128];
        }
#pragma unroll
        for (int s = 16; s >= 1; s >>= 1) {
            a0 += __shfl_xor(a0, s);
            a1 += __shfl_xor(a1, s);
            a2 += __shfl_xor(a2, s);
        }
        if ((lane & 31) == 0) {
            if (mm < NMEM) {
                const int pei = perow[mm];
                const float msk = (1.0f - maskrow[mm]) * -100.0f;
                p_lds[wave][h0][mm] = a0 + peT[pei * HEADS + h0] + msk;
                p_lds[wave][h1][mm] = a1 + peT[pei * HEADS + h1] + msk;
                p_lds[wave][h2][mm] = a2 + peT[pei * HEADS + h2] + msk;
            } else {
                p_lds[wave][h0][NMEM] = fminf(fmaxf(a0, -5.f), 5.f);
                p_lds[wave][h1][NMEM] = fminf(fmaxf(a1, -5.f), 5.f);
                p_lds[wave][h2][NMEM] = fminf(fmaxf(a2, -5.f), 5.f);
            }
        }
    }
    // wave-local softmax over 49 entries per head: 8 lanes per head
    {
        const int hh = lane >> 3, sub = lane & 7;
        if (hh < HEADS) {
            float mx = -1e30f;
            for (int j = sub; j < NMEM + 1; j += 8) mx = fmaxf(mx, p_lds[wave][hh][j]);
#pragma unroll
            for (int s = 4; s; s >>= 1) mx = fmaxf(mx, __shfl_xor(mx, s));
            float sum = 0.f;
            for (int j = sub; j < NMEM + 1; j += 8) {
                float e = __expf(p_lds[wave][hh][j] - mx);
                p_lds[wave][hh][j] = e;
                sum += e;
            }
#pragma unroll
            for (int s = 4; s; s >>= 1) sum += __shfl_xor(sum, s);
            const float inv = 1.0f / sum;
            for (int j = sub; j < NMEM + 1; j += 8) p_lds[wave][hh][j] *= inv;
        }
    }
    // PV
    float o0 = 0.f, o1 = 0.f, o2 = 0.f;
#pragma unroll 4
    for (int mm = 0; mm < NMEM; ++mm) {
        const int mem = mrow[mm];
        const float* vrow = v + (size_t)(bbase + mem) * DIMC;
        o0 += p_lds[wave][h0][mm] * vrow[lane];
        o1 += p_lds[wave][h1][mm] * vrow[lane + 64];
        o2 += p_lds[wave][h2][mm] * vrow[lane + 128];
    }
    o0 += p_lds[wave][h0][NMEM] * blank_v[lane];
    o1 += p_lds[wave][h1][NMEM] * blank_v[lane + 64];
    o2 += p_lds[wave][h2][NMEM] * blank_v[lane + 128];
    float* orow = outA + (size_t)qi * DIMC;
    orow[lane] = o0; orow[lane + 64] = o1; orow[lane + 128] = o2;
}

extern "C" void kernel_launch(void* const* d_in, const int* in_sizes, int n_in,
                              void* d_out, int out_size, void* d_ws, size_t ws_size,
                              hipStream_t stream) {
    const float* feat      = (const float*)d_in[0];
    const int*   member_i  = (const int*)d_in[1];
    const float* cmask     = (const float*)d_in[2];
    const int*   pe_idx    = (const int*)d_in[3];
    // d_in[4] = global_attn (0 in this benchmark)
    const float* Wq        = (const float*)d_in[5];
    const float* bq        = (const float*)d_in[6];
    const float* Wkv       = (const float*)d_in[7];
    const float* bkv       = (const float*)d_in[8];
    const float* Wpe       = (const float*)d_in[9];
    const float* bpe       = (const float*)d_in[10];
    const float* blank_k   = (const float*)d_in[11];
    const float* blank_v   = (const float*)d_in[12];
    const float* Wproj     = (const float*)d_in[13];
    const float* bproj     = (const float*)d_in[14];
    const float* pre_table = (const float*)d_in[15];
    float* out = (float*)d_out;

    const size_t SZ = (size_t)NTOT * DIMC * sizeof(float);  // 12.58 MB
    const size_t NEED = 4 * SZ + (size_t)PE_N * HEADS * sizeof(float);
    if (ws_size < NEED) return;  // scratch too small: fail visibly, don't scribble OOB

    char* ws = (char*)d_ws;
    float* q    = (float*)(ws);
    float* k    = (float*)(ws + SZ);
    float* v    = (float*)(ws + 2 * SZ);
    float* outA = (float*)(ws + 3 * SZ);
    float* peT  = (float*)(ws + 4 * SZ);

    pe_kernel<<<(PE_N + 255) / 256, 256, 0, stream>>>(pre_table, Wpe, bpe, peT);
    gemm_kernel<<<dim3(NTOT / BM, (DIMC * 3) / BN), 256, 0, stream>>>(
        feat, Wq, Wkv, bq, bkv, q, k, v, 0);
    attn_kernel<<<NTOT / 4, 256, 0, stream>>>(q, k, v, member_i, cmask, pe_idx, peT,
                                              blank_k, blank_v, outA);
    gemm_kernel<<<dim3(NTOT / BM, DIMC / BN), 256, 0, stream>>>(
        outA, Wproj, nullptr, bproj, nullptr, out, nullptr, nullptr, 1);
}

// Round 2
// 185.891 us; speedup vs baseline: 2.0396x; 2.0396x over previous
//
#include <hip/hip_runtime.h>
#include <hip/hip_fp16.h>

#define DIMC 192
#define HEADS 6
#define NSEQ 8192
#define NB 2
#define NMEM 48
#define PE_N 2601
#define NTOT (NB * NSEQ)   // 16384

typedef _Float16 f16;
typedef __attribute__((ext_vector_type(4))) _Float16 f16x4;
typedef __attribute__((ext_vector_type(8))) _Float16 f16x8;
typedef __attribute__((ext_vector_type(4))) float f32x4;
typedef __attribute__((ext_vector_type(4))) int i32x4;

// ---------------- PE table: (2601,5) @ Wpe^T (5->6) + bpe (fp32) ----------------
__global__ void pe_kernel(const float* __restrict__ pre_table,
                          const float* __restrict__ Wpe,
                          const float* __restrict__ bpe,
                          float* __restrict__ pe_out) {
    int i = blockIdx.x * blockDim.x + threadIdx.x;
    if (i >= PE_N) return;
    float p0 = pre_table[i * 5 + 0], p1 = pre_table[i * 5 + 1], p2 = pre_table[i * 5 + 2];
    float p3 = pre_table[i * 5 + 3], p4 = pre_table[i * 5 + 4];
#pragma unroll
    for (int h = 0; h < HEADS; ++h) {
        float s = bpe[h] + p0 * Wpe[h * 5 + 0] + p1 * Wpe[h * 5 + 1] + p2 * Wpe[h * 5 + 2]
                + p3 * Wpe[h * 5 + 3] + p4 * Wpe[h * 5 + 4];
        pe_out[i * HEADS + h] = s;
    }
}

// ---------------- fp32 -> fp16 conversion of feat / weights / blanks ----------------
#define FEAT4 (NTOT * DIMC / 4)     // 786432
#define WQ4   (DIMC * DIMC / 4)     // 9216
#define WKV4  (2 * DIMC * DIMC / 4) // 18432
#define BL4   (DIMC / 4)            // 48
__global__ __launch_bounds__(256) void cvt_kernel(
    const float* __restrict__ feat, const float* __restrict__ Wq,
    const float* __restrict__ Wkv, const float* __restrict__ Wproj,
    const float* __restrict__ blank_k, const float* __restrict__ blank_v,
    f16* __restrict__ featH, f16* __restrict__ WqH, f16* __restrict__ WkvH,
    f16* __restrict__ WprojH, f16* __restrict__ bkH, f16* __restrict__ bvH) {
    const int total = FEAT4 + WQ4 + WKV4 + WQ4 + BL4 + BL4;
    for (int i = blockIdx.x * 256 + threadIdx.x; i < total; i += gridDim.x * 256) {
        const float* src; f16* dst; int j = i;
        if (j < FEAT4)             { src = feat;    dst = featH; }
        else if ((j -= FEAT4) < WQ4)  { src = Wq;      dst = WqH; }
        else if ((j -= WQ4) < WKV4)   { src = Wkv;     dst = WkvH; }
        else if ((j -= WKV4) < WQ4)   { src = Wproj;   dst = WprojH; }
        else if ((j -= WQ4) < BL4)    { src = blank_k; dst = bkH; }
        else { j -= BL4;              src = blank_v;   dst = bvH; }
        float4 f = *reinterpret_cast<const float4*>(src + (size_t)j * 4);
        f16x4 h = {(f16)f.x, (f16)f.y, (f16)f.z, (f16)f.w};
        *reinterpret_cast<f16x4*>(dst + (size_t)j * 4) = h;
    }
}

// ---------------- fp16 MFMA GEMM: C[i][o] = dot(A[i,:192], W[o,:192]) ----------------
// Tile 64x64, whole K=192 resident in LDS. A and W staged via global_load_lds (16B)
// with XOR chunk swizzle applied on the SOURCE address (LDS stays linear per rule:
// gload_lds dest = wave-uniform base + lane*16). Fragment ds_read applies same XOR.
// mode 0: qkv (grid.y=9; col<192 -> q*scale; col>=192 -> de-interleave k/v, all fp16 out)
// mode 1: proj (grid.y=3; fp32 out + bias)
__global__ __launch_bounds__(256) void gemm16_kernel(
    const f16* __restrict__ A, const f16* __restrict__ Wa, const f16* __restrict__ Wb,
    const float* __restrict__ b0, const float* __restrict__ bkv,
    f16* __restrict__ oq, f16* __restrict__ ok, f16* __restrict__ ov,
    float* __restrict__ ofp, const int mode) {
    __shared__ f16 As[64 * DIMC];   // 24 KB
    __shared__ f16 Bs[64 * DIMC];   // 24 KB
    const int tid = threadIdx.x, w = tid >> 6, l = tid & 63;
    const size_t rowbase = (size_t)blockIdx.x * 64;
    const int colbase = blockIdx.y * 64;
    const f16* Wsel = (mode == 0 && colbase >= DIMC) ? (Wb + (size_t)(colbase - DIMC) * DIMC)
                                                     : (Wa + (size_t)colbase * DIMC);
    const char* Abase = (const char*)(A + rowbase * DIMC);
    const char* Wbase = (const char*)Wsel;
#pragma unroll
    for (int i = 0; i < 6; ++i) {
        const int L = (w * 6 + i) * 64 + l;          // 16B-chunk index, 0..1535
        const int row = L / 24, cp = L % 24;         // 24 chunks per 384B row
        const int coff = ((cp ^ (row & 7)) << 4);
        __builtin_amdgcn_global_load_lds(
            (const __attribute__((address_space(1))) unsigned int*)(Abase + row * 384 + coff),
            (__attribute__((address_space(3))) unsigned int*)(As + (size_t)(w * 6 + i) * 512),
            16, 0, 0);
        __builtin_amdgcn_global_load_lds(
            (const __attribute__((address_space(1))) unsigned int*)(Wbase + row * 384 + coff),
            (__attribute__((address_space(3))) unsigned int*)(Bs + (size_t)(w * 6 + i) * 512),
            16, 0, 0);
    }
    __syncthreads();
    const int lm = l & 15, lg = l >> 4, sw = l & 7;
    const int wr = w & 1, wc = w >> 1;
    f32x4 acc[2][2];
    acc[0][0] = acc[0][1] = acc[1][0] = acc[1][1] = (f32x4){0.f, 0.f, 0.f, 0.f};
    const char* AsB = (const char*)As;
    const char* BsB = (const char*)Bs;
    const int ar0 = (wr * 32 + lm) * 384, ar1 = (wr * 32 + 16 + lm) * 384;
    const int br0 = (wc * 32 + lm) * 384, br1 = (wc * 32 + 16 + lm) * 384;
#pragma unroll
    for (int ks = 0; ks < 6; ++ks) {
        const int ch = ((ks * 4 + lg) ^ sw) << 4;
        f16x8 a0 = *reinterpret_cast<const f16x8*>(AsB + ar0 + ch);
        f16x8 a1 = *reinterpret_cast<const f16x8*>(AsB + ar1 + ch);
        f16x8 q0 = *reinterpret_cast<const f16x8*>(BsB + br0 + ch);
        f16x8 q1 = *reinterpret_cast<const f16x8*>(BsB + br1 + ch);
        acc[0][0] = __builtin_amdgcn_mfma_f32_16x16x32_f16(a0, q0, acc[0][0], 0, 0, 0);
        acc[0][1] = __builtin_amdgcn_mfma_f32_16x16x32_f16(a0, q1, acc[0][1], 0, 0, 0);
        acc[1][0] = __builtin_amdgcn_mfma_f32_16x16x32_f16(a1, q0, acc[1][0], 0, 0, 0);
        acc[1][1] = __builtin_amdgcn_mfma_f32_16x16x32_f16(a1, q1, acc[1][1], 0, 0, 0);
    }
#pragma unroll
    for (int fm = 0; fm < 2; ++fm)
#pragma unroll
        for (int fn = 0; fn < 2; ++fn) {
            const int col = colbase + wc * 32 + fn * 16 + lm;
            const size_t r0 = rowbase + wr * 32 + fm * 16 + lg * 4;
            if (mode == 1) {
                const float bias = b0[col];
#pragma unroll
                for (int r = 0; r < 4; ++r)
                    ofp[(r0 + r) * DIMC + col] = acc[fm][fn][r] + bias;
            } else if (col < DIMC) {
                const float bias = b0[col];
#pragma unroll
                for (int r = 0; r < 4; ++r)
                    oq[(r0 + r) * DIMC + col] =
                        (f16)((acc[fm][fn][r] + bias) * 0.17677669529663687f);
            } else {
                const int t0 = col - DIMC;
                const float bias = bkv[t0];
                const int hh = t0 >> 6, rr = t0 & 63;
                f16* dst = (rr < 32) ? (ok + hh * 32 + rr) : (ov + hh * 32 + (rr - 32));
#pragma unroll
                for (int r = 0; r < 4; ++r)
                    dst[(r0 + r) * DIMC] = (f16)(acc[fm][fn][r] + bias);
            }
        }
}

// ---------------- attention: one wave per query, 2 lanes per member for QK ----------------
__global__ __launch_bounds__(256) void attn_kernel(
    const f16* __restrict__ qH, const f16* __restrict__ kH, const f16* __restrict__ vH,
    const f16* __restrict__ bkH, const f16* __restrict__ bvH,
    const int* __restrict__ member_idx, const float* __restrict__ cmask,
    const int* __restrict__ pe_idx, const float* __restrict__ peT,
    f16* __restrict__ outA) {
    __shared__ float p_lds[4][HEADS][64];
    __shared__ int m_lds[4][64];
    const int wave = threadIdx.x >> 6, lane = threadIdx.x & 63;
    const int qi = blockIdx.x * 4 + wave;
    const int bbase = qi & ~(NSEQ - 1);
    if (lane < NMEM)
        m_lds[wave][lane] = bbase + member_idx[(size_t)qi * NMEM + lane];
    __syncthreads();
    // ---- phase 1: logits. lane pair (2m, 2m+1): s=0 -> heads 0-2 (ch 0..95), s=1 -> heads 3-5
    const int s = lane & 1, ms = lane >> 1;
    const f16* qbase = qH + (size_t)qi * DIMC + s * 96;
#pragma unroll
    for (int pass = 0; pass < 2; ++pass) {
        const int m = pass * 32 + ms;
        const bool act = (m <= NMEM);
        const f16* kp;
        if (act && m < NMEM) kp = kH + (size_t)m_lds[wave][m] * DIMC + s * 96;
        else                 kp = bkH + s * 96;
        float a0 = 0.f, a1 = 0.f, a2 = 0.f;
#pragma unroll
        for (int j = 0; j < 12; ++j) {
            f16x8 qv = *reinterpret_cast<const f16x8*>(qbase + j * 8);
            f16x8 kd = *reinterpret_cast<const f16x8*>(kp + j * 8);
            float d = (float)qv[0] * (float)kd[0] + (float)qv[1] * (float)kd[1]
                    + (float)qv[2] * (float)kd[2] + (float)qv[3] * (float)kd[3]
                    + (float)qv[4] * (float)kd[4] + (float)qv[5] * (float)kd[5]
                    + (float)qv[6] * (float)kd[6] + (float)qv[7] * (float)kd[7];
            if (j < 4)      a0 += d;
            else if (j < 8) a1 += d;
            else            a2 += d;
        }
        if (act) {
            p_lds[wave][3 * s + 0][m] = a0;
            p_lds[wave][3 * s + 1][m] = a1;
            p_lds[wave][3 * s + 2][m] = a2;
        }
    }
    __syncthreads();
    // ---- phase 2: softmax across lanes (member-per-lane; 49 active)
    {
        const int m = lane;
        float lo[HEADS];
#pragma unroll
        for (int h = 0; h < HEADS; ++h)
            lo[h] = (m <= NMEM) ? p_lds[wave][h][m] : -1e30f;
        if (m < NMEM) {
            const int pei = pe_idx[(size_t)qi * NMEM + m];
            const float msk = (1.0f - cmask[(size_t)qi * NMEM + m]) * -100.0f;
#pragma unroll
            for (int h = 0; h < HEADS; ++h) lo[h] += peT[pei * HEADS + h] + msk;
        } else if (m == NMEM) {
#pragma unroll
            for (int h = 0; h < HEADS; ++h) lo[h] = fminf(fmaxf(lo[h], -5.f), 5.f);
        }
#pragma unroll
        for (int h = 0; h < HEADS; ++h) {
            float mx = lo[h];
#pragma unroll
            for (int st = 32; st; st >>= 1) mx = fmaxf(mx, __shfl_xor(mx, st));
            const float e = __expf(lo[h] - mx);
            float sm = e;
#pragma unroll
            for (int st = 32; st; st >>= 1) sm += __shfl_xor(sm, st);
            p_lds[wave][h][m] = e / sm;   // overwrite raw logits with weights
        }
    }
    __syncthreads();
    // ---- phase 3: PV. lane owns channels {lane, lane+64, lane+128}
    const int h0 = lane >> 5;
    float o0 = 0.f, o1 = 0.f, o2 = 0.f;
#pragma unroll 4
    for (int mm = 0; mm < NMEM; mm += 4) {
        const i32x4 rows = *reinterpret_cast<const i32x4*>(&m_lds[wave][mm]);
        const f32x4 w0 = *reinterpret_cast<const f32x4*>(&p_lds[wave][h0][mm]);
        const f32x4 w1 = *reinterpret_cast<const f32x4*>(&p_lds[wave][h0 + 2][mm]);
        const f32x4 w2 = *reinterpret_cast<const f32x4*>(&p_lds[wave][h0 + 4][mm]);
#pragma unroll
        for (int t = 0; t < 4; ++t) {
            const f16* vp = vH + (size_t)rows[t] * DIMC;
            o0 += w0[t] * (float)vp[lane];
            o1 += w1[t] * (float)vp[64 + lane];
            o2 += w2[t] * (float)vp[128 + lane];
        }
    }
    o0 += p_lds[wave][h0][NMEM]     * (float)bvH[lane];
    o1 += p_lds[wave][h0 + 2][NMEM] * (float)bvH[64 + lane];
    o2 += p_lds[wave][h0 + 4][NMEM] * (float)bvH[128 + lane];
    f16* orow = outA + (size_t)qi * DIMC;
    orow[lane] = (f16)o0; orow[64 + lane] = (f16)o1; orow[128 + lane] = (f16)o2;
}

extern "C" void kernel_launch(void* const* d_in, const int* in_sizes, int n_in,
                              void* d_out, int out_size, void* d_ws, size_t ws_size,
                              hipStream_t stream) {
    const float* feat      = (const float*)d_in[0];
    const int*   member_i  = (const int*)d_in[1];
    const float* cmask     = (const float*)d_in[2];
    const int*   pe_idx    = (const int*)d_in[3];
    // d_in[4] = global_attn (0 in this benchmark)
    const float* Wq        = (const float*)d_in[5];
    const float* bq        = (const float*)d_in[6];
    const float* Wkv       = (const float*)d_in[7];
    const float* bkv       = (const float*)d_in[8];
    const float* Wpe       = (const float*)d_in[9];
    const float* bpe       = (const float*)d_in[10];
    const float* blank_k   = (const float*)d_in[11];
    const float* blank_v   = (const float*)d_in[12];
    const float* Wproj     = (const float*)d_in[13];
    const float* bproj     = (const float*)d_in[14];
    const float* pre_table = (const float*)d_in[15];
    float* out = (float*)d_out;

    const size_t SZH = (size_t)NTOT * DIMC * sizeof(f16);  // 6.29 MB
    char* ws = (char*)d_ws;
    f16* qH     = (f16*)(ws);
    f16* kH     = (f16*)(ws + SZH);
    f16* vH     = (f16*)(ws + 2 * SZH);
    f16* outAH  = (f16*)(ws + 3 * SZH);
    f16* featH  = (f16*)(ws + 4 * SZH);
    char* p = ws + 5 * SZH;
    f16* WqH    = (f16*)p;              p += (size_t)DIMC * DIMC * 2;
    f16* WkvH   = (f16*)p;              p += (size_t)2 * DIMC * DIMC * 2;
    f16* WprojH = (f16*)p;              p += (size_t)DIMC * DIMC * 2;
    f16* bkH    = (f16*)p;              p += 512;
    f16* bvH    = (f16*)p;              p += 512;
    float* peT  = (float*)p;            p += (size_t)PE_N * HEADS * sizeof(float);
    if ((size_t)(p - ws) > ws_size) return;  // fail visibly rather than scribble OOB

    pe_kernel<<<(PE_N + 255) / 256, 256, 0, stream>>>(pre_table, Wpe, bpe, peT);
    cvt_kernel<<<1024, 256, 0, stream>>>(feat, Wq, Wkv, Wproj, blank_k, blank_v,
                                         featH, WqH, WkvH, WprojH, bkH, bvH);
    gemm16_kernel<<<dim3(NTOT / 64, 9), 256, 0, stream>>>(
        featH, WqH, WkvH, bq, bkv, qH, kH, vH, nullptr, 0);
    attn_kernel<<<NTOT / 4, 256, 0, stream>>>(qH, kH, vH, bkH, bvH, member_i, cmask,
                                              pe_idx, peT, outAH);
    gemm16_kernel<<<dim3(NTOT / 64, 3), 256, 0, stream>>>(
        outAH, WprojH, nullptr, bproj, nullptr, nullptr, nullptr, nullptr, out, 1);
}